// Round 5
// baseline (66.672 us; speedup 1.0000x reference)
//
#include <hip/hip_runtime.h>

// EfficientRelativePositionalEncoding, MI355X (gfx950)
// B=2, N=2048, H=8, HID=16.  out[b][h][i][j], fp32, 268 MB write-bound.
//
// Single kernel. Folded math (computed per-lane at block start, weights are
// L1/L2-resident after the first block):
//   Afold[k][h] = sum_m Wd2[k][m] * Wf[m][h]        (16x8)
//   Bfold[k][h] = sum_m Wr2[k][m] * Wf[m+8][h]      (16x8)
//   c[h]        = bf[h] + bd2@Wf[0:8] + br2@Wf[8:16]
//
// Per 32-pair tile: D = Wc^T . F via two chained mfma_f32_32x32x16_f16
// (K-half 1: dist feats, K-half 2: dir feats). A and B frags use the SAME
// (lane-group, elem)->k convention so any bijective HW k-permutation cancels.
// C/D layout (HW-verified): col = lane&31, row = (reg&3)+8*(reg>>2)+4*(lane>>5)
//   -> regs 0..3 hold h = reg + 4*(lane>>5), cols = pairs.
// Feature layer computed in PACKED f16 (v_pk_fma_f16 / v_pk_max_f16), weights
// pre-packed f16x2 -> B-frags need no cvt/pack epilogue.
// Output bias folded into loop-invariant MFMA C-in tuple (D != C, no movs).
// Direct global stores: per reg r, lanes 0-31 write 128B contiguous in plane
// h=r, lanes 32-63 in plane h=r+4. No LDS, no barriers, waves independent.

#define BB 2
#define NN 2048
#define HH 8

typedef _Float16 f16x2  __attribute__((ext_vector_type(2)));
typedef _Float16 f16x8  __attribute__((ext_vector_type(8)));
typedef float    f32x16 __attribute__((ext_vector_type(16)));

union B8 { f16x2 p[4]; f16x8 v; };

static __device__ __forceinline__ f16x2 pkrtz(float a, float b) {
    return __builtin_bit_cast(f16x2, __builtin_amdgcn_cvt_pkrtz(a, b));
}

// grid = B*N blocks (4096), 256 threads = 4 waves; wave w owns j in [512w, 512w+512)
__global__ __launch_bounds__(256) void erpe_main(
    const float* __restrict__ xyz,
    const float* __restrict__ Wd1, const float* __restrict__ bd1,
    const float* __restrict__ Wd2, const float* __restrict__ bd2,
    const float* __restrict__ Wr1, const float* __restrict__ br1,
    const float* __restrict__ Wr2, const float* __restrict__ br2,
    const float* __restrict__ Wf,  const float* __restrict__ bf,
    float* __restrict__ out)
{
    const int tid  = threadIdx.x;
    const int wave = tid >> 6;
    const int lane = tid & 63;
    const int g    = lane >> 5;        // k-half group within frag
    const int jl   = lane & 31;        // pair-column within tile / h-row for A

    const int blk = blockIdx.x;
    const int i   = blk & (NN - 1);
    const int b   = blk >> 11;

    // ---- packed feature-layer weights: elem e=2p+s -> k = kb+e ----
    const int kb = g * 8;
    f16x2 wdp[4], bdp[4], w0p[4], w1p[4], w2p[4], brp[4];
    #pragma unroll
    for (int p = 0; p < 4; ++p) {
        const int k0 = kb + 2 * p;
        wdp[p][0] = (_Float16)Wd1[k0];     wdp[p][1] = (_Float16)Wd1[k0 + 1];
        bdp[p][0] = (_Float16)bd1[k0];     bdp[p][1] = (_Float16)bd1[k0 + 1];
        w0p[p][0] = (_Float16)Wr1[k0];     w0p[p][1] = (_Float16)Wr1[k0 + 1];
        w1p[p][0] = (_Float16)Wr1[16+k0];  w1p[p][1] = (_Float16)Wr1[16+k0+1];
        w2p[p][0] = (_Float16)Wr1[32+k0];  w2p[p][1] = (_Float16)Wr1[32+k0+1];
        brp[p][0] = (_Float16)br1[k0];     brp[p][1] = (_Float16)br1[k0 + 1];
    }

    // ---- per-lane weight fold: A frags (row h = jl, zero for h>=8) ----
    const int hA = jl & 7;
    f16x8 A1, A2;
    #pragma unroll
    for (int e = 0; e < 8; ++e) {
        float sa = 0.f, sb = 0.f;
        #pragma unroll
        for (int m = 0; m < 8; ++m) {
            sa = fmaf(Wd2[(kb + e) * 8 + m], Wf[m * 8 + hA], sa);
            sb = fmaf(Wr2[(kb + e) * 8 + m], Wf[(m + 8) * 8 + hA], sb);
        }
        A1[e] = (jl < 8) ? (_Float16)sa : (_Float16)0.f;
        A2[e] = (jl < 8) ? (_Float16)sb : (_Float16)0.f;
    }

    // ---- output bias for this lane's h rows, folded into MFMA C-in ----
    f32x16 accInit;
    #pragma unroll
    for (int q = 0; q < 16; ++q) accInit[q] = 0.f;
    #pragma unroll
    for (int r = 0; r < 4; ++r) {
        const int h = g * 4 + r;
        float s = bf[h];
        #pragma unroll
        for (int m = 0; m < 8; ++m)
            s = fmaf(bd2[m], Wf[m * 8 + h],
                fmaf(br2[m], Wf[(m + 8) * 8 + h], s));
        accInit[r] = s;
    }

    const float* xb = xyz + (size_t)b * NN * 3;
    const float xi = xb[i * 3 + 0];
    const float yi = xb[i * 3 + 1];
    const float zi = xb[i * 3 + 2];

    float* op = out + ((size_t)b * HH + 4 * g) * (size_t)NN * NN
                    + (size_t)i * NN + wave * 512 + jl;

    const f16x2 z2 = { (_Float16)0.f, (_Float16)0.f };

    for (int t2 = 0; t2 < 16; ++t2) {      // 16 tiles of 32 j per wave
        const int j = wave * 512 + t2 * 32 + jl;
        const float ax = xb[j * 3 + 0];
        const float ay = xb[j * 3 + 1];
        const float az = xb[j * 3 + 2];
        const float dx = ax - xi, dy = ay - yi, dz = az - zi;
        const float r2 = fmaf(dx, dx, fmaf(dy, dy, dz * dz));
        const float d  = __builtin_amdgcn_sqrtf(r2);
        const float inv = __builtin_amdgcn_rcpf(d + 1e-7f);
        const float ux = dx * inv, uy = dy * inv, uz = dz * inv;

        const f16x2 d2  = pkrtz(d, d);
        const f16x2 ux2 = pkrtz(ux, ux);
        const f16x2 uy2 = pkrtz(uy, uy);
        const f16x2 uz2 = pkrtz(uz, uz);

        B8 Btd, Btr;
        #pragma unroll
        for (int p = 0; p < 4; ++p) {
            f16x2 td = d2 * wdp[p] + bdp[p];
            f16x2 tr = ux2 * w0p[p] + (uy2 * w1p[p] + (uz2 * w2p[p] + brp[p]));
            Btd.p[p] = __builtin_elementwise_max(td, z2);
            Btr.p[p] = __builtin_elementwise_max(tr, z2);
        }

        f32x16 acc;
        acc = __builtin_amdgcn_mfma_f32_32x32x16_f16(A1, Btd.v, accInit, 0, 0, 0);
        acc = __builtin_amdgcn_mfma_f32_32x32x16_f16(A2, Btr.v, acc,     0, 0, 0);

        // direct store: reg r -> plane h = r + 4*g, col j
        #pragma unroll
        for (int r = 0; r < 4; ++r)
            op[(size_t)r * NN * NN + t2 * 32] = acc[r];
    }
}

extern "C" void kernel_launch(void* const* d_in, const int* in_sizes, int n_in,
                              void* d_out, int out_size, void* d_ws, size_t ws_size,
                              hipStream_t stream) {
    const float* xyz = (const float*)d_in[0];
    const float* Wd1 = (const float*)d_in[1];
    const float* bd1 = (const float*)d_in[2];
    const float* Wd2 = (const float*)d_in[3];
    const float* bd2 = (const float*)d_in[4];
    const float* Wr1 = (const float*)d_in[5];
    const float* br1 = (const float*)d_in[6];
    const float* Wr2 = (const float*)d_in[7];
    const float* br2 = (const float*)d_in[8];
    const float* Wf  = (const float*)d_in[9];
    const float* bf  = (const float*)d_in[10];
    float* out = (float*)d_out;

    erpe_main<<<BB * NN, 256, 0, stream>>>(xyz, Wd1, bd1, Wd2, bd2,
                                           Wr1, br1, Wr2, br2, Wf, bf, out);
}

// Round 6
// 52.381 us; speedup vs baseline: 1.2728x; 1.2728x over previous
//
#include <hip/hip_runtime.h>

// EfficientRelativePositionalEncoding, MI355X (gfx950)
// B=2, N=2048, H=8, HID=16.  out[b][h][i][j], fp32, 268 MB write-bound.
//
// Two kernels:
//  1) erpe_fold (1 block): folds second-layer+fusion weights and pre-bakes
//     MFMA-ready f16 tables into ws:
//       f16 ws[   0.. 511]: A1 table [32 rows][16 k], rows 8..31 = 0
//                           rows 0..7: Afold[k][h]=sum_m Wd2[k][m]*Wf[m][h]
//       f16 ws[ 512..1023]: A2 table, same shape, Bfold (Wr2 x Wf[8:16])
//       f16 ws[1024..1119]: feature weights k-ordered: Wd1,bd1,Wr1r0,r1,r2,br1
//       f32 ws32[560..567]: c[h] = bf + bd2@Wf[0:8] + br2@Wf[8:16]
//  2) erpe_main (B*N blocks x 256): per 32-pair tile,
//     D = Wc^T . F via two chained mfma_f32_32x32x16_f16
//     (K-half 1: dist feats, K-half 2: dir feats). A and B frags use the SAME
//     (lane-group, elem)->k convention so any HW k-permutation cancels.
//     C/D (HW-verified): col=lane&31, row regs 0..3 -> h = reg + 4*(lane>>5).
//     Feature layer in PACKED f16 (v_pk_fma_f16/v_pk_max_f16), B-frags need
//     no cvt epilogue. Output bias in loop-invariant MFMA C-in.
//     Direct global stores: per reg, two fully-written 128B segments/instr.
//     No LDS, no barriers, waves independent.

#define BB 2
#define NN 2048
#define HH 8

typedef _Float16 f16x2  __attribute__((ext_vector_type(2)));
typedef _Float16 f16x8  __attribute__((ext_vector_type(8)));
typedef float    f32x16 __attribute__((ext_vector_type(16)));

union W8 { f16x8 v; f16x2 p[4]; };

static __device__ __forceinline__ f16x2 pkrtz(float a, float b) {
    return __builtin_bit_cast(f16x2, __builtin_amdgcn_cvt_pkrtz(a, b));
}

__global__ __launch_bounds__(256) void erpe_fold(
    const float* __restrict__ Wd1, const float* __restrict__ bd1,
    const float* __restrict__ Wd2, const float* __restrict__ bd2,
    const float* __restrict__ Wr1, const float* __restrict__ br1,
    const float* __restrict__ Wr2, const float* __restrict__ br2,
    const float* __restrict__ Wf,  const float* __restrict__ bf,
    void* __restrict__ ws)
{
    _Float16* wsf = (_Float16*)ws;
    float*    wsf32 = (float*)ws;
    const int t = threadIdx.x;

    if (t < 128) {                       // k = t>>3, h = t&7
        const int k = t >> 3, h = t & 7;
        float sa = 0.f, sb = 0.f;
        #pragma unroll
        for (int m = 0; m < 8; ++m) {
            sa = fmaf(Wd2[k * 8 + m], Wf[m * 8 + h], sa);
            sb = fmaf(Wr2[k * 8 + m], Wf[(m + 8) * 8 + h], sb);
        }
        wsf[h * 16 + k]       = (_Float16)sa;   // A1 table row h
        wsf[512 + h * 16 + k] = (_Float16)sb;   // A2 table row h
    }
    // zero rows 8..31 of both tables (f16 indices 128..511 per table)
    for (int idx = t; idx < 384; idx += 256) {
        wsf[128 + idx]       = (_Float16)0.f;
        wsf[512 + 128 + idx] = (_Float16)0.f;
    }
    if (t < 16) {                        // feature weights, k-ordered f16
        wsf[1024 + t] = (_Float16)Wd1[t];
        wsf[1040 + t] = (_Float16)bd1[t];
        wsf[1056 + t] = (_Float16)Wr1[t];
        wsf[1072 + t] = (_Float16)Wr1[16 + t];
        wsf[1088 + t] = (_Float16)Wr1[32 + t];
        wsf[1104 + t] = (_Float16)br1[t];
    }
    if (t < 8) {                         // c[h], f32 at float index 560+
        float s = bf[t];
        #pragma unroll
        for (int m = 0; m < 8; ++m)
            s = fmaf(bd2[m], Wf[m * 8 + t],
                fmaf(br2[m], Wf[(m + 8) * 8 + t], s));
        wsf32[560 + t] = s;
    }
}

// grid = B*N blocks (4096), 256 threads = 4 waves; wave w owns j in [512w, 512w+512)
__global__ __launch_bounds__(256) void erpe_main(
    const float* __restrict__ xyz,
    const void* __restrict__ ws,
    float* __restrict__ out)
{
    const _Float16* wsf   = (const _Float16*)ws;
    const float*    wsf32 = (const float*)ws;

    const int tid  = threadIdx.x;
    const int wave = tid >> 6;
    const int lane = tid & 63;
    const int g    = lane >> 5;        // k-half group within frag
    const int jl   = lane & 31;        // pair-column within tile / h-row for A
    const int kb   = g * 8;

    const int blk = blockIdx.x;
    const int i   = blk & (NN - 1);
    const int b   = blk >> 11;

    // ---- MFMA-ready A fragments: one b128 load each ----
    const f16x8 A1 = *(const f16x8*)(wsf + jl * 16 + kb);
    const f16x8 A2 = *(const f16x8*)(wsf + 512 + jl * 16 + kb);

    // ---- packed feature-layer weights: one b128 load per set ----
    const W8 wd  = { *(const f16x8*)(wsf + 1024 + kb) };
    const W8 bd  = { *(const f16x8*)(wsf + 1040 + kb) };
    const W8 w0  = { *(const f16x8*)(wsf + 1056 + kb) };
    const W8 w1  = { *(const f16x8*)(wsf + 1072 + kb) };
    const W8 w2  = { *(const f16x8*)(wsf + 1088 + kb) };
    const W8 br  = { *(const f16x8*)(wsf + 1104 + kb) };

    // ---- output bias folded into loop-invariant MFMA C-in ----
    f32x16 accInit;
    #pragma unroll
    for (int q = 0; q < 16; ++q) accInit[q] = 0.f;
    #pragma unroll
    for (int r = 0; r < 4; ++r) accInit[r] = wsf32[560 + g * 4 + r];

    const float* xb = xyz + (size_t)b * NN * 3;
    const float xi = xb[i * 3 + 0];
    const float yi = xb[i * 3 + 1];
    const float zi = xb[i * 3 + 2];

    float* op = out + ((size_t)b * HH + 4 * g) * (size_t)NN * NN
                    + (size_t)i * NN + wave * 512 + jl;

    const f16x2 z2 = { (_Float16)0.f, (_Float16)0.f };

    for (int t2 = 0; t2 < 16; ++t2) {      // 16 tiles of 32 j per wave
        const int j = wave * 512 + t2 * 32 + jl;
        const float ax = xb[j * 3 + 0];
        const float ay = xb[j * 3 + 1];
        const float az = xb[j * 3 + 2];
        const float dx = ax - xi, dy = ay - yi, dz = az - zi;
        const float r2 = fmaf(dx, dx, fmaf(dy, dy, dz * dz));
        const float d  = __builtin_amdgcn_sqrtf(r2);
        const float inv = __builtin_amdgcn_rcpf(d + 1e-7f);
        const float ux = dx * inv, uy = dy * inv, uz = dz * inv;

        const f16x2 d2  = pkrtz(d, d);
        const f16x2 ux2 = pkrtz(ux, ux);
        const f16x2 uy2 = pkrtz(uy, uy);
        const f16x2 uz2 = pkrtz(uz, uz);

        W8 Btd, Btr;
        #pragma unroll
        for (int p = 0; p < 4; ++p) {
            f16x2 td = d2 * wd.p[p] + bd.p[p];
            f16x2 tr = ux2 * w0.p[p] + (uy2 * w1.p[p] + (uz2 * w2.p[p] + br.p[p]));
            Btd.p[p] = __builtin_elementwise_max(td, z2);
            Btr.p[p] = __builtin_elementwise_max(tr, z2);
        }

        f32x16 acc;
        acc = __builtin_amdgcn_mfma_f32_32x32x16_f16(A1, Btd.v, accInit, 0, 0, 0);
        acc = __builtin_amdgcn_mfma_f32_32x32x16_f16(A2, Btr.v, acc,     0, 0, 0);

        // direct store: reg r -> plane h = r + 4*g, col j
        #pragma unroll
        for (int r = 0; r < 4; ++r)
            op[(size_t)r * NN * NN + t2 * 32] = acc[r];
    }
}

extern "C" void kernel_launch(void* const* d_in, const int* in_sizes, int n_in,
                              void* d_out, int out_size, void* d_ws, size_t ws_size,
                              hipStream_t stream) {
    const float* xyz = (const float*)d_in[0];
    const float* Wd1 = (const float*)d_in[1];
    const float* bd1 = (const float*)d_in[2];
    const float* Wd2 = (const float*)d_in[3];
    const float* bd2 = (const float*)d_in[4];
    const float* Wr1 = (const float*)d_in[5];
    const float* br1 = (const float*)d_in[6];
    const float* Wr2 = (const float*)d_in[7];
    const float* br2 = (const float*)d_in[8];
    const float* Wf  = (const float*)d_in[9];
    const float* bf  = (const float*)d_in[10];
    float* out = (float*)d_out;

    erpe_fold<<<1, 256, 0, stream>>>(Wd1, bd1, Wd2, bd2, Wr1, br1,
                                     Wr2, br2, Wf, bf, d_ws);
    erpe_main<<<BB * NN, 256, 0, stream>>>(xyz, d_ws, out);
}

// Round 7
// 51.406 us; speedup vs baseline: 1.2970x; 1.0190x over previous
//
#include <hip/hip_runtime.h>

// EfficientRelativePositionalEncoding, MI355X (gfx950)
// B=2, N=2048, H=8, HID=16.  out[b][h][i][j], fp32, 268 MB write-bound.
//
// Two kernels:
//  1) erpe_fold (1 block): folds second-layer+fusion weights and pre-bakes
//     MFMA-ready f16 tables into ws (see R6 comment block).
//  2) erpe_main (B*N blocks x 256): per 32-pair tile,
//     D = Wc^T . F via two chained mfma_f32_32x32x16_f16
//     (K-half 1: dist feats, K-half 2: dir feats). A and B frags use the SAME
//     (lane-group, elem)->k convention so any HW k-permutation cancels.
//     C/D (HW-verified): col=lane&31, row regs 0..3 -> h = reg + 4*(lane>>5).
//     Feature layer in PACKED f16; output bias in loop-invariant MFMA C-in.
//     R7 changes: uniform-SGPR-base + u32 voffset addressing for all global
//     accesses; 16-tile loop FULLY UNROLLED so per-tile offsets (t2*128B
//     stores / t2*384B loads) fold into the 13-bit instruction immediates ->
//     zero per-tile address VALU. VALU/tile ~40 instrs < HBM drain ~90cy.
//     __launch_bounds__(256,4) caps VGPR at 128 (4 waves/SIMD).

#define BB 2
#define NN 2048
#define HH 8

typedef _Float16 f16x2  __attribute__((ext_vector_type(2)));
typedef _Float16 f16x8  __attribute__((ext_vector_type(8)));
typedef float    f32x16 __attribute__((ext_vector_type(16)));

union W8 { f16x8 v; f16x2 p[4]; };

static __device__ __forceinline__ f16x2 pkrtz(float a, float b) {
    return __builtin_bit_cast(f16x2, __builtin_amdgcn_cvt_pkrtz(a, b));
}

__global__ __launch_bounds__(256) void erpe_fold(
    const float* __restrict__ Wd1, const float* __restrict__ bd1,
    const float* __restrict__ Wd2, const float* __restrict__ bd2,
    const float* __restrict__ Wr1, const float* __restrict__ br1,
    const float* __restrict__ Wr2, const float* __restrict__ br2,
    const float* __restrict__ Wf,  const float* __restrict__ bf,
    void* __restrict__ ws)
{
    _Float16* wsf = (_Float16*)ws;
    float*    wsf32 = (float*)ws;
    const int t = threadIdx.x;

    if (t < 128) {                       // k = t>>3, h = t&7
        const int k = t >> 3, h = t & 7;
        float sa = 0.f, sb = 0.f;
        #pragma unroll
        for (int m = 0; m < 8; ++m) {
            sa = fmaf(Wd2[k * 8 + m], Wf[m * 8 + h], sa);
            sb = fmaf(Wr2[k * 8 + m], Wf[(m + 8) * 8 + h], sb);
        }
        wsf[h * 16 + k]       = (_Float16)sa;   // A1 table row h
        wsf[512 + h * 16 + k] = (_Float16)sb;   // A2 table row h
    }
    // zero rows 8..31 of both tables (f16 indices 128..511 per table)
    for (int idx = t; idx < 384; idx += 256) {
        wsf[128 + idx]       = (_Float16)0.f;
        wsf[512 + 128 + idx] = (_Float16)0.f;
    }
    if (t < 16) {                        // feature weights, k-ordered f16
        wsf[1024 + t] = (_Float16)Wd1[t];
        wsf[1040 + t] = (_Float16)bd1[t];
        wsf[1056 + t] = (_Float16)Wr1[t];
        wsf[1072 + t] = (_Float16)Wr1[16 + t];
        wsf[1088 + t] = (_Float16)Wr1[32 + t];
        wsf[1104 + t] = (_Float16)br1[t];
    }
    if (t < 8) {                         // c[h], f32 at float index 560+
        float s = bf[t];
        #pragma unroll
        for (int m = 0; m < 8; ++m)
            s = fmaf(bd2[m], Wf[m * 8 + t],
                fmaf(br2[m], Wf[(m + 8) * 8 + t], s));
        wsf32[560 + t] = s;
    }
}

// grid = B*N blocks (4096), 256 threads = 4 waves; wave w owns j in [512w, 512w+512)
__global__ __launch_bounds__(256, 4) void erpe_main(
    const float* __restrict__ xyz,
    const void* __restrict__ ws,
    float* __restrict__ out)
{
    const _Float16* wsf   = (const _Float16*)ws;
    const float*    wsf32 = (const float*)ws;

    const int tid  = threadIdx.x;
    const int wave = tid >> 6;
    const int lane = tid & 63;
    const int g    = lane >> 5;        // k-half group within frag
    const int jl   = lane & 31;        // pair-column within tile / h-row for A
    const int kb   = g * 8;

    const int blk = blockIdx.x;
    const int i   = blk & (NN - 1);
    const int b   = blk >> 11;

    // ---- MFMA-ready A fragments: one b128 load each ----
    const f16x8 A1 = *(const f16x8*)(wsf + jl * 16 + kb);
    const f16x8 A2 = *(const f16x8*)(wsf + 512 + jl * 16 + kb);

    // ---- packed feature-layer weights: one b128 load per set ----
    const W8 wd  = { *(const f16x8*)(wsf + 1024 + kb) };
    const W8 bd  = { *(const f16x8*)(wsf + 1040 + kb) };
    const W8 w0  = { *(const f16x8*)(wsf + 1056 + kb) };
    const W8 w1  = { *(const f16x8*)(wsf + 1072 + kb) };
    const W8 w2  = { *(const f16x8*)(wsf + 1088 + kb) };
    const W8 br  = { *(const f16x8*)(wsf + 1104 + kb) };

    // ---- output bias folded into loop-invariant MFMA C-in ----
    f32x16 accInit;
    #pragma unroll
    for (int q = 0; q < 16; ++q) accInit[q] = 0.f;
    #pragma unroll
    for (int r = 0; r < 4; ++r) accInit[r] = wsf32[560 + g * 4 + r];

    // ---- uniform SGPR bases + per-lane u32 voffsets ----
    const float* xb = xyz + (size_t)b * NN * 3;                 // uniform
    const float xi = xb[i * 3 + 0];
    const float yi = xb[i * 3 + 1];
    const float zi = xb[i * 3 + 2];

    float* pb = out + ((size_t)b * HH) * (size_t)NN * NN + (size_t)i * NN; // uniform
    const unsigned v0 = (unsigned)(4 * g) * (NN * NN) + wave * 512 + jl;
    unsigned voff[4];
    #pragma unroll
    for (int r = 0; r < 4; ++r) voff[r] = v0 + (unsigned)r * (NN * NN);

    const unsigned vx0 = (unsigned)(wave * 512 + jl) * 3;

    const f16x2 z2 = { (_Float16)0.f, (_Float16)0.f };

    #pragma unroll
    for (int t2 = 0; t2 < 16; ++t2) {      // 16 tiles of 32 j per wave
        const unsigned vx = vx0 + t2 * 96;
        const float ax = xb[vx + 0];
        const float ay = xb[vx + 1];
        const float az = xb[vx + 2];
        const float dx = ax - xi, dy = ay - yi, dz = az - zi;
        const float r2 = fmaf(dx, dx, fmaf(dy, dy, dz * dz));
        const float d  = __builtin_amdgcn_sqrtf(r2);
        const float inv = __builtin_amdgcn_rcpf(d + 1e-7f);
        const float ux = dx * inv, uy = dy * inv, uz = dz * inv;

        const f16x2 d2  = pkrtz(d, d);
        const f16x2 ux2 = pkrtz(ux, ux);
        const f16x2 uy2 = pkrtz(uy, uy);
        const f16x2 uz2 = pkrtz(uz, uz);

        W8 Btd, Btr;
        #pragma unroll
        for (int p = 0; p < 4; ++p) {
            f16x2 td = d2 * wd.p[p] + bd.p[p];
            f16x2 tr = ux2 * w0.p[p] + (uy2 * w1.p[p] + (uz2 * w2.p[p] + br.p[p]));
            Btd.p[p] = __builtin_elementwise_max(td, z2);
            Btr.p[p] = __builtin_elementwise_max(tr, z2);
        }

        f32x16 acc;
        acc = __builtin_amdgcn_mfma_f32_32x32x16_f16(A1, Btd.v, accInit, 0, 0, 0);
        acc = __builtin_amdgcn_mfma_f32_32x32x16_f16(A2, Btr.v, acc,     0, 0, 0);

        // direct store: reg r -> plane h = r + 4*g, col j; t2*32 folds to imm
        #pragma unroll
        for (int r = 0; r < 4; ++r)
            pb[voff[r] + t2 * 32] = acc[r];
    }
}

extern "C" void kernel_launch(void* const* d_in, const int* in_sizes, int n_in,
                              void* d_out, int out_size, void* d_ws, size_t ws_size,
                              hipStream_t stream) {
    const float* xyz = (const float*)d_in[0];
    const float* Wd1 = (const float*)d_in[1];
    const float* bd1 = (const float*)d_in[2];
    const float* Wd2 = (const float*)d_in[3];
    const float* bd2 = (const float*)d_in[4];
    const float* Wr1 = (const float*)d_in[5];
    const float* br1 = (const float*)d_in[6];
    const float* Wr2 = (const float*)d_in[7];
    const float* br2 = (const float*)d_in[8];
    const float* Wf  = (const float*)d_in[9];
    const float* bf  = (const float*)d_in[10];
    float* out = (float*)d_out;

    erpe_fold<<<1, 256, 0, stream>>>(Wd1, bd1, Wd2, bd2, Wr1, br1,
                                     Wr2, br2, Wf, bf, d_ws);
    erpe_main<<<BB * NN, 256, 0, stream>>>(xyz, d_ws, out);
}

// Round 8
// 47.124 us; speedup vs baseline: 1.4148x; 1.0909x over previous
//
#include <hip/hip_runtime.h>

// EfficientRelativePositionalEncoding, MI355X (gfx950)
// B=2, N=2048, H=8, HID=16.  out[b][h][i][j], fp32, 268 MB write-bound.
//
// SINGLE kernel (R8): the weight fold runs as a block-parallel LDS prologue
// (128 threads x 8 FMAs + one barrier) instead of a separate 1-block dispatch
// that serialized the whole GPU (R7: ~3-5us). NOT R5's per-lane serial fold.
//   sA1[32r][16k]: rows 0..7 = Afold[k][h]=sum_m Wd2[k][m]*Wf[m][h], rows 8+ = 0
//   sA2[32r][16k]: same with Wr2 x Wf[8:16]
//   sW[6][16]:     f16 feature weights k-ordered: Wd1,bd1,Wr1r0,r1,r2,br1
//   sC[8]:         c[h] = bf + bd2@Wf[0:8] + br2@Wf[8:16]  (f32)
//
// Main loop (= R7, known-good): per 32-pair tile,
//   D = Wc^T . F via two chained mfma_f32_32x32x16_f16
//   (K-half 1: dist feats, K-half 2: dir feats). A and B frags use the SAME
//   (lane-group, elem)->k convention so any HW k-permutation cancels.
//   C/D (HW-verified): col=lane&31, row regs 0..3 -> h = reg + 4*(lane>>5).
//   Feature layer in PACKED f16; output bias in loop-invariant MFMA C-in.
//   Uniform-SGPR base + u32 voffsets; 16-tile loop fully unrolled so t2*128B
//   folds into the 13-bit store immediate. Direct global stores: per reg,
//   two fully-written 128B segments/instr. No inter-wave dependencies.

#define BB 2
#define NN 2048
#define HH 8

typedef _Float16 f16x2  __attribute__((ext_vector_type(2)));
typedef _Float16 f16x8  __attribute__((ext_vector_type(8)));
typedef float    f32x16 __attribute__((ext_vector_type(16)));

union W8 { f16x8 v; f16x2 p[4]; };

static __device__ __forceinline__ f16x2 pkrtz(float a, float b) {
    return __builtin_bit_cast(f16x2, __builtin_amdgcn_cvt_pkrtz(a, b));
}

// grid = B*N blocks (4096), 256 threads = 4 waves; wave w owns j in [512w, 512w+512)
__global__ __launch_bounds__(256, 4) void erpe_main(
    const float* __restrict__ xyz,
    const float* __restrict__ Wd1, const float* __restrict__ bd1,
    const float* __restrict__ Wd2, const float* __restrict__ bd2,
    const float* __restrict__ Wr1, const float* __restrict__ br1,
    const float* __restrict__ Wr2, const float* __restrict__ br2,
    const float* __restrict__ Wf,  const float* __restrict__ bf,
    float* __restrict__ out)
{
    __shared__ _Float16 sA1[32 * 16];   // [row h(pad 32)][k 16]
    __shared__ _Float16 sA2[32 * 16];
    __shared__ _Float16 sW[6 * 16];     // wd, bd, w0, w1, w2, br (k-ordered)
    __shared__ float    sC[8];

    const int t = threadIdx.x;

    // ---- block-parallel fold prologue ----
    for (int idx = t; idx < 384; idx += 256) {   // zero rows 8..31
        sA1[128 + idx] = (_Float16)0.f;
        sA2[128 + idx] = (_Float16)0.f;
    }
    if (t < 128) {                               // k = t>>3, h = t&7
        const int k = t >> 3, h = t & 7;
        float sa = 0.f, sb = 0.f;
        #pragma unroll
        for (int m = 0; m < 8; ++m) {
            sa = fmaf(Wd2[k * 8 + m], Wf[m * 8 + h], sa);
            sb = fmaf(Wr2[k * 8 + m], Wf[(m + 8) * 8 + h], sb);
        }
        sA1[h * 16 + k] = (_Float16)sa;
        sA2[h * 16 + k] = (_Float16)sb;
    }
    if (t < 16) {                                // feature weights, f16
        sW[t]      = (_Float16)Wd1[t];
        sW[16 + t] = (_Float16)bd1[t];
        sW[32 + t] = (_Float16)Wr1[t];
        sW[48 + t] = (_Float16)Wr1[16 + t];
        sW[64 + t] = (_Float16)Wr1[32 + t];
        sW[80 + t] = (_Float16)br1[t];
    }
    if (t < 8) {                                 // c[h]
        float s = bf[t];
        #pragma unroll
        for (int m = 0; m < 8; ++m)
            s = fmaf(bd2[m], Wf[m * 8 + t],
                fmaf(br2[m], Wf[(m + 8) * 8 + t], s));
        sC[t] = s;
    }
    __syncthreads();

    const int wave = t >> 6;
    const int lane = t & 63;
    const int g    = lane >> 5;        // k-half group within frag
    const int jl   = lane & 31;        // pair-column within tile / h-row for A
    const int kb   = g * 8;

    const int blk = blockIdx.x;
    const int i   = blk & (NN - 1);
    const int b   = blk >> 11;

    // ---- MFMA-ready A fragments + packed weights from LDS ----
    const f16x8 A1 = *(const f16x8*)(sA1 + jl * 16 + kb);
    const f16x8 A2 = *(const f16x8*)(sA2 + jl * 16 + kb);
    const W8 wd = { *(const f16x8*)(sW + kb) };
    const W8 bd = { *(const f16x8*)(sW + 16 + kb) };
    const W8 w0 = { *(const f16x8*)(sW + 32 + kb) };
    const W8 w1 = { *(const f16x8*)(sW + 48 + kb) };
    const W8 w2 = { *(const f16x8*)(sW + 64 + kb) };
    const W8 br = { *(const f16x8*)(sW + 80 + kb) };

    // ---- output bias folded into loop-invariant MFMA C-in ----
    f32x16 accInit;
    #pragma unroll
    for (int q = 0; q < 16; ++q) accInit[q] = 0.f;
    #pragma unroll
    for (int r = 0; r < 4; ++r) accInit[r] = sC[g * 4 + r];

    // ---- uniform SGPR bases + per-lane u32 voffsets ----
    const float* xb = xyz + (size_t)b * NN * 3;                 // uniform
    const float xi = xb[i * 3 + 0];
    const float yi = xb[i * 3 + 1];
    const float zi = xb[i * 3 + 2];

    float* pb = out + ((size_t)b * HH) * (size_t)NN * NN + (size_t)i * NN; // uniform
    const unsigned v0 = (unsigned)(4 * g) * (NN * NN) + wave * 512 + jl;
    unsigned voff[4];
    #pragma unroll
    for (int r = 0; r < 4; ++r) voff[r] = v0 + (unsigned)r * (NN * NN);

    const unsigned vx0 = (unsigned)(wave * 512 + jl) * 3;

    const f16x2 z2 = { (_Float16)0.f, (_Float16)0.f };

    #pragma unroll
    for (int t2 = 0; t2 < 16; ++t2) {      // 16 tiles of 32 j per wave
        const unsigned vx = vx0 + t2 * 96;
        const float ax = xb[vx + 0];
        const float ay = xb[vx + 1];
        const float az = xb[vx + 2];
        const float dx = ax - xi, dy = ay - yi, dz = az - zi;
        const float r2 = fmaf(dx, dx, fmaf(dy, dy, dz * dz));
        const float d  = __builtin_amdgcn_sqrtf(r2);
        const float inv = __builtin_amdgcn_rcpf(d + 1e-7f);
        const float ux = dx * inv, uy = dy * inv, uz = dz * inv;

        const f16x2 d2  = pkrtz(d, d);
        const f16x2 ux2 = pkrtz(ux, ux);
        const f16x2 uy2 = pkrtz(uy, uy);
        const f16x2 uz2 = pkrtz(uz, uz);

        W8 Btd, Btr;
        #pragma unroll
        for (int p = 0; p < 4; ++p) {
            f16x2 td = d2 * wd.p[p] + bd.p[p];
            f16x2 tr = ux2 * w0.p[p] + (uy2 * w1.p[p] + (uz2 * w2.p[p] + br.p[p]));
            Btd.p[p] = __builtin_elementwise_max(td, z2);
            Btr.p[p] = __builtin_elementwise_max(tr, z2);
        }

        f32x16 acc;
        acc = __builtin_amdgcn_mfma_f32_32x32x16_f16(A1, Btd.v, accInit, 0, 0, 0);
        acc = __builtin_amdgcn_mfma_f32_32x32x16_f16(A2, Btr.v, acc,     0, 0, 0);

        // direct store: reg r -> plane h = r + 4*g, col j; t2*32 folds to imm
        #pragma unroll
        for (int r = 0; r < 4; ++r)
            pb[voff[r] + t2 * 32] = acc[r];
    }
}

extern "C" void kernel_launch(void* const* d_in, const int* in_sizes, int n_in,
                              void* d_out, int out_size, void* d_ws, size_t ws_size,
                              hipStream_t stream) {
    const float* xyz = (const float*)d_in[0];
    const float* Wd1 = (const float*)d_in[1];
    const float* bd1 = (const float*)d_in[2];
    const float* Wd2 = (const float*)d_in[3];
    const float* bd2 = (const float*)d_in[4];
    const float* Wr1 = (const float*)d_in[5];
    const float* br1 = (const float*)d_in[6];
    const float* Wr2 = (const float*)d_in[7];
    const float* br2 = (const float*)d_in[8];
    const float* Wf  = (const float*)d_in[9];
    const float* bf  = (const float*)d_in[10];
    float* out = (float*)d_out;

    erpe_main<<<BB * NN, 256, 0, stream>>>(xyz, Wd1, bd1, Wd2, bd2,
                                           Wr1, br1, Wr2, br2, Wf, bf, out);
}